// Round 18
// baseline (38.298 us; speedup 1.0000x reference)
//
#include <hip/hip_runtime.h>
#include <hip/hip_bf16.h>

#define NQ     8
#define SEQL   128
#define BATCHN 256
#define EMBED  512
#define DIN    520          // EMBED + NQ
#define GSTR   32           // 4 gates * 8 qubits
#define GBSTR  40           // gbuf row stride (floats)
#define INV2PI 0.15915494309189535f
#define WROW   524          // Wlds padded row (shorts) -> conflict-free b128

typedef __attribute__((ext_vector_type(8))) short  bf16x8;
typedef __attribute__((ext_vector_type(4))) float  f32x4;
typedef unsigned int uint2v __attribute__((ext_vector_type(2)));

// 8 f32 -> bf16x8 via hardware v_cvt_pk_bf16_f32 (RNE)
__device__ __forceinline__ bf16x8 cvt8(float4 u, float4 v) {
    union { unsigned w[4]; bf16x8 v8; } r;
    asm("v_cvt_pk_bf16_f32 %0, %1, %2" : "=v"(r.w[0]) : "v"(u.x), "v"(u.y));
    asm("v_cvt_pk_bf16_f32 %0, %1, %2" : "=v"(r.w[1]) : "v"(u.z), "v"(u.w));
    asm("v_cvt_pk_bf16_f32 %0, %1, %2" : "=v"(r.w[2]) : "v"(v.x), "v"(v.y));
    asm("v_cvt_pk_bf16_f32 %0, %1, %2" : "=v"(r.w[3]) : "v"(v.z), "v"(v.w));
    return r.v8;
}

// ---------------------------------------------------------------------------
// DPP helpers
// ---------------------------------------------------------------------------
#define DPP_QP(a,b,c,d) ((a)|((b)<<2)|((c)<<4)|((d)<<6))
#define DPP_SHL(n) (0x100+(n))
#define DPP_SHR(n) (0x110+(n))

template<int CTRL>
__device__ __forceinline__ float updpf(float old_, float src) {
    return __int_as_float(__builtin_amdgcn_update_dpp(
        __float_as_int(old_), __float_as_int(src), CTRL, 0xF, 0xF, false));
}

// value at lane^16 / lane^32 (XOR-extract, semantics-proof; r8/r6-proven)
__device__ __forceinline__ float xor16f(float x) {
    unsigned xu = (unsigned)__float_as_int(x);
    uint2v r = __builtin_amdgcn_permlane16_swap(xu, xu, false, false);
    return __int_as_float((int)(r.x ^ r.y ^ xu));
}
__device__ __forceinline__ float xor32f(float x) {
    unsigned xu = (unsigned)__float_as_int(x);
    uint2v r = __builtin_amdgcn_permlane32_swap(xu, xu, false, false);
    return __int_as_float((int)(r.x ^ r.y ^ xu));
}

__device__ __forceinline__ float frcp(float x) { return __builtin_amdgcn_rcpf(x); }
__device__ __forceinline__ float fexp2(float x) { return __builtin_amdgcn_exp2f(x); }

#define LOG2E  1.4426950408889634f
#define LOG2E2 2.8853900817779268f

// one LSTM step — guard-free scan (qubit group at DPP-row base => out-of-row
// row_shr auto-fills 1.0), gate gather via permlane16/32 row exchanges.
#define QSTEP(GV) do {                                                        \
    float sA = fmaf(H[0],Whp[0],fmaf(H[1],Whp[1],fmaf(H[2],Whp[2],H[3]*Whp[3]))); \
    float sB = fmaf(H[4],Whp[4],fmaf(H[5],Whp[5],fmaf(H[6],Whp[6],H[7]*Whp[7]))); \
    float cs = __builtin_amdgcn_cosf((GV) + sA + sB);                         \
    float p = cs;                                                             \
    p *= updpf<DPP_SHR(1)>(1.0f, p);                                          \
    p *= updpf<DPP_SHR(2)>(1.0f, p);                                          \
    p *= updpf<DPP_SHR(4)>(1.0f, p);                                          \
    float v = jz ? 1.0f : cs;                                                 \
    v *= updpf<DPP_QP(1,0,3,2)>(v, v);                                        \
    v *= updpf<DPP_QP(2,3,0,1)>(v, v);                                        \
    float xl = updpf<DPP_SHL(4)>(v, v);                                       \
    float xr = updpf<DPP_SHR(4)>(v, v);                                       \
    v *= (m4 ? xr : xl);                                                      \
    float qv = jz ? v : p;                                                    \
    float act = fmaf(sk, frcp(1.0f + fexp2(ek * qv)), ok);                    \
    float A_ = act;                                                           \
    float B_ = xor16f(A_);              /* gate g^1 */                        \
    float C_ = xor32f(A_);              /* gate g^2 */                        \
    float D_ = xor16f(C_);              /* gate g^3 */                        \
    float fv = (g==0) ? A_ : (g==1) ? B_ : (g==2) ? C_ : D_;                  \
    float iv = (g==0) ? B_ : (g==1) ? A_ : (g==2) ? D_ : C_;                  \
    float uv = (g==0) ? C_ : (g==1) ? D_ : (g==2) ? A_ : B_;                  \
    float ov = (g==0) ? D_ : (g==1) ? C_ : (g==2) ? B_ : A_;                  \
    c_own = fmaf(fv, c_own, iv * uv);                                         \
    float tc = fmaf(-2.0f, frcp(1.0f + fexp2(LOG2E2 * c_own)), 1.0f);         \
    h_own = ov * tc;                                                          \
    H[0] = h_own;                                                             \
    H[1] = updpf<DPP_QP(1,0,3,2)>(H[0], H[0]);                                \
    H[2] = updpf<DPP_QP(2,3,0,1)>(H[0], H[0]);                                \
    H[3] = updpf<DPP_QP(2,3,0,1)>(H[1], H[1]);                                \
    _Pragma("unroll")                                                         \
    for (int rr = 0; rr < 4; ++rr) {                                          \
        float yl = updpf<DPP_SHL(4)>(H[rr], H[rr]);                           \
        float yr = updpf<DPP_SHR(4)>(H[rr], H[rr]);                           \
        H[4 + rr] = m4 ? yr : yl;                                             \
    }                                                                         \
} while (0)

// producer: gather chunk CH's 16 emb rows, MFMA vs Wlds, write G vals to DST.
#define PRODUCE(DST, CH) do {                                                 \
    int tok_ = sent[((CH) * 16 + lm) * BATCHN + b];                           \
    const float* ar_ = emb + (size_t)tok_ * EMBED;                            \
    float4 ua[16], va[16];                                                    \
    _Pragma("unroll")                                                         \
    for (int kc = 0; kc < 16; ++kc) {                                         \
        ua[kc] = *reinterpret_cast<const float4*>(ar_ + kc * 32 + q * 8);     \
        va[kc] = *reinterpret_cast<const float4*>(ar_ + kc * 32 + q * 8 + 4); \
    }                                                                         \
    f32x4 acc0 = {0.f,0.f,0.f,0.f};                                           \
    f32x4 acc1 = {0.f,0.f,0.f,0.f};                                           \
    _Pragma("unroll")                                                         \
    for (int kc = 0; kc < 16; ++kc) {                                         \
        bf16x8 a_ = cvt8(ua[kc], va[kc]);                                     \
        const int kl_ = kc * 32 + q * 8;                                      \
        bf16x8 b0_ = *reinterpret_cast<const bf16x8*>(&Wlds[lm][kl_]);        \
        bf16x8 b1_ = *reinterpret_cast<const bf16x8*>(&Wlds[16 + lm][kl_]);   \
        acc0 = __builtin_amdgcn_mfma_f32_16x16x32_bf16(a_, b0_, acc0, 0,0,0); \
        acc1 = __builtin_amdgcn_mfma_f32_16x16x32_bf16(a_, b1_, acc1, 0,0,0); \
    }                                                                         \
    _Pragma("unroll")                                                         \
    for (int r_ = 0; r_ < 4; ++r_) {                                          \
        (DST)[(4*q + r_) * GBSTR + lm]      = fmaf(acc0[r_], INV2PI, bc0);    \
        (DST)[(4*q + r_) * GBSTR + 16 + lm] = fmaf(acc1[r_], INV2PI, bc1);    \
    }                                                                         \
} while (0)

// ---------------------------------------------------------------------------
// Wave-specialized fused kernel: 256 blocks x 128 threads (2 waves).
//   wave 0 (consumer): serial LSTM chain; lane = gate*16 + j (qubit group at
//   DPP-row base -> guard-free scan); lanes 8-15 of each row idle-compute.
//   wave 1 (producer): emb gather + MFMA for chunk c+1 while consumer runs c.
// ---------------------------------------------------------------------------
__global__ __launch_bounds__(128, 1)
void k_fused(const int* __restrict__ sent, const float* __restrict__ emb,
             const float* __restrict__ Wf, const float* __restrict__ Wi,
             const float* __restrict__ Wu, const float* __restrict__ Wo,
             const float* __restrict__ bf, const float* __restrict__ bi,
             const float* __restrict__ bu, const float* __restrict__ bo,
             const float* __restrict__ thf, const float* __restrict__ thi,
             const float* __restrict__ thu, const float* __restrict__ tho,
             float* __restrict__ out)
{
    __shared__ short Wlds[32][WROW];        // 33.5 KB bf16, [c][k 0..511]
    __shared__ float gbuf[2][16 * GBSTR];   // 5.1 KB double-buffered chunk

    const int tid = threadIdx.x;            // 0..127
    const int b   = blockIdx.x;             // batch row
    const bool producer = (tid >= 64);
    const int g   = (tid >> 4) & 3;         // consumer: gate = DPP row
    const int j   = tid & 7;                // consumer: qubit
    const int lm  = tid & 15;               // producer A-row / B-col
    const int q   = (tid >> 4) & 3;         // producer k-quarter

    // ---- stage W -> bf16 LDS, 128 threads cooperatively ----
    {
        const int c = tid & 31, seg = tid >> 5;     // seg 0..3 x 128 floats
        const int gg = c >> 3, jj = c & 7;
        const float* W = (gg==0) ? Wf : (gg==1) ? Wi : (gg==2) ? Wu : Wo;
        const float* src = W + (size_t)jj * DIN + seg * 128;
        #pragma unroll
        for (int p = 0; p < 16; ++p) {
            float4 u = *reinterpret_cast<const float4*>(src + p * 8);
            float4 v = *reinterpret_cast<const float4*>(src + p * 8 + 4);
            *reinterpret_cast<bf16x8*>(&Wlds[c][seg * 128 + p * 8]) = cvt8(u, v);
        }
    }

    // ---- role-specific persistent state ----
    float Whp[8], H[8];
    float c_own = 0.f, h_own = 0.f;
    float bc0 = 0.f, bc1 = 0.f;
    bool  m4 = false, jz = false;
    float ek = 0.f, sk = 0.f, ok = 0.f;

    if (producer) {
        const int g0 = lm >> 3, j0 = lm & 7;        // col lm -> gate 0/1
        const float* B0 = (g0==0) ? bf  : bi;
        const float* T0 = (g0==0) ? thf : thi;
        bc0 = (B0[j0] + T0[j0]) * INV2PI;
        const float* B1 = (g0==0) ? bu  : bo;       // col 16+lm -> gate 2/3
        const float* T1 = (g0==0) ? thu : tho;
        bc1 = (B1[j0] + T1[j0]) * INV2PI;
    } else {
        const float* Wsel = (g==0) ? Wf : (g==1) ? Wi : (g==2) ? Wu : Wo;
        #pragma unroll
        for (int rr = 0; rr < 8; ++rr) {
            Whp[rr] = Wsel[j * DIN + EMBED + (j ^ rr)] * INV2PI;
            H[rr]   = 0.f;
        }
        m4 = (j >= 4); jz = (j == 0);
        const bool isU = (g == 2);
        ek = isU ? LOG2E2 : -LOG2E;
        sk = isU ? -2.0f  : 1.0f;
        ok = isU ? 1.0f   : 0.0f;
    }
    __syncthreads();                         // Wlds ready

    if (producer) PRODUCE(&gbuf[0][0], 0);   // prologue: chunk 0
    __syncthreads();                         // gbuf[0] ready

    const int gidx = g * 8 + j;              // consumer G column

    #pragma unroll 1
    for (int c = 0; c < 8; ++c) {
        if (producer) {
            if (c < 7) PRODUCE(&gbuf[(c + 1) & 1][0], c + 1);
        } else {
            const float* gc = &gbuf[c & 1][gidx];
            float gvv[16];
            #pragma unroll
            for (int s = 0; s < 16; ++s) gvv[s] = gc[s * GBSTR];
            #pragma unroll
            for (int s = 0; s < 16; ++s) QSTEP(gvv[s]);
        }
        __syncthreads();
    }

    if (tid < 8) out[b * NQ + tid] = h_own;  // consumer row 0 (g=0), j=tid
}

// ---------------------------------------------------------------------------
extern "C" void kernel_launch(void* const* d_in, const int* in_sizes, int n_in,
                              void* d_out, int out_size, void* d_ws, size_t ws_size,
                              hipStream_t stream)
{
    const int*   sent = (const int*)  d_in[0];
    // d_in[1] = features : unused by the reference
    const float* emb  = (const float*)d_in[2];
    const float* Wf   = (const float*)d_in[3];
    const float* bf   = (const float*)d_in[4];
    const float* Wi   = (const float*)d_in[5];
    const float* bi   = (const float*)d_in[6];
    const float* Wu   = (const float*)d_in[7];
    const float* bu   = (const float*)d_in[8];
    const float* Wo   = (const float*)d_in[9];
    const float* bo   = (const float*)d_in[10];
    const float* thf  = (const float*)d_in[11];
    const float* thi  = (const float*)d_in[12];
    const float* thu  = (const float*)d_in[13];
    const float* tho  = (const float*)d_in[14];
    float* out = (float*)d_out;

    k_fused<<<BATCHN, 128, 0, stream>>>(sent, emb, Wf, Wi, Wu, Wo,
                                        bf, bi, bu, bo,
                                        thf, thi, thu, tho, out);
}

// Round 19
// 35.999 us; speedup vs baseline: 1.0639x; 1.0639x over previous
//
#include <hip/hip_runtime.h>
#include <hip/hip_bf16.h>

#define NQ     8
#define SEQL   128
#define BATCHN 256
#define EMBED  512
#define DIN    520          // EMBED + NQ
#define GSTR   32           // 4 gates * 8 qubits
#define GBSTR  40           // gbuf row stride (floats)
#define INV2PI 0.15915494309189535f
#define WROW   524          // Wlds padded row (shorts) -> conflict-free b128

typedef __attribute__((ext_vector_type(8))) short  bf16x8;
typedef __attribute__((ext_vector_type(4))) float  f32x4;
typedef unsigned int uint2v __attribute__((ext_vector_type(2)));

// 8 f32 -> bf16x8 via hardware v_cvt_pk_bf16_f32 (RNE)
__device__ __forceinline__ bf16x8 cvt8(float4 u, float4 v) {
    union { unsigned w[4]; bf16x8 v8; } r;
    asm("v_cvt_pk_bf16_f32 %0, %1, %2" : "=v"(r.w[0]) : "v"(u.x), "v"(u.y));
    asm("v_cvt_pk_bf16_f32 %0, %1, %2" : "=v"(r.w[1]) : "v"(u.z), "v"(u.w));
    asm("v_cvt_pk_bf16_f32 %0, %1, %2" : "=v"(r.w[2]) : "v"(v.x), "v"(v.y));
    asm("v_cvt_pk_bf16_f32 %0, %1, %2" : "=v"(r.w[3]) : "v"(v.z), "v"(v.w));
    return r.v8;
}

// ---------------------------------------------------------------------------
// DPP helpers
// ---------------------------------------------------------------------------
#define DPP_QP(a,b,c,d) ((a)|((b)<<2)|((c)<<4)|((d)<<6))
#define DPP_SHL(n) (0x100+(n))
#define DPP_SHR(n) (0x110+(n))
#define DPP_ROR(n) (0x120+(n))

template<int CTRL>
__device__ __forceinline__ float updpf(float old_, float src) {
    return __int_as_float(__builtin_amdgcn_update_dpp(
        __float_as_int(old_), __float_as_int(src), CTRL, 0xF, 0xF, false));
}

// value at lane^16 (XOR-extract, semantics-proof)
__device__ __forceinline__ float xor16f(float x) {
    unsigned xu = (unsigned)__float_as_int(x);
    uint2v r = __builtin_amdgcn_permlane16_swap(xu, xu, false, false);
    return __int_as_float((int)(r.x ^ r.y ^ xu));
}

__device__ __forceinline__ float frcp(float x) { return __builtin_amdgcn_rcpf(x); }
__device__ __forceinline__ float fexp2(float x) { return __builtin_amdgcn_exp2f(x); }

#define LOG2E  1.4426950408889634f
#define LOG2E2 2.8853900817779268f

// one LSTM step (r8/r17-proven math, 32-lane layout l32 = g*8+j)
#define QSTEP(GV) do {                                                        \
    float sA = fmaf(H[0],Whp[0],fmaf(H[1],Whp[1],fmaf(H[2],Whp[2],H[3]*Whp[3]))); \
    float sB = fmaf(H[4],Whp[4],fmaf(H[5],Whp[5],fmaf(H[6],Whp[6],H[7]*Whp[7]))); \
    float cs = __builtin_amdgcn_cosf((GV) + sA + sB);                         \
    float p = cs, s;                                                          \
    s = updpf<DPP_SHR(1)>(1.0f, p); p *= (m1 ? s : 1.0f);                     \
    s = updpf<DPP_SHR(2)>(1.0f, p); p *= (m2 ? s : 1.0f);                     \
    s = updpf<DPP_SHR(4)>(1.0f, p); p *= (m4 ? s : 1.0f);                     \
    float v = jz ? 1.0f : cs;                                                 \
    v *= updpf<DPP_QP(1,0,3,2)>(v, v);                                        \
    v *= updpf<DPP_QP(2,3,0,1)>(v, v);                                        \
    float xl = updpf<DPP_SHL(4)>(v, v);                                       \
    float xr = updpf<DPP_SHR(4)>(v, v);                                       \
    v *= (m4 ? xr : xl);                                                      \
    float qv = jz ? v : p;                                                    \
    float act = fmaf(sk, frcp(1.0f + fexp2(ek * qv)), ok);                    \
    float A_  = act;                                                          \
    float B8  = updpf<DPP_ROR(8)>(A_, A_);                                    \
    float C16 = xor16f(A_);                                                   \
    float D24 = updpf<DPP_ROR(8)>(C16, C16);                                  \
    float fv = (g==0) ? A_ : (g==1) ? B8 : (g==2) ? C16 : D24;                \
    float iv = (g==1) ? A_ : (g==0) ? B8 : (g==3) ? C16 : D24;                \
    float uv = (g==2) ? A_ : (g==3) ? B8 : (g==0) ? C16 : D24;                \
    float ov = (g==3) ? A_ : (g==2) ? B8 : (g==1) ? C16 : D24;                \
    c_own = fmaf(fv, c_own, iv * uv);                                         \
    float tc = fmaf(-2.0f, frcp(1.0f + fexp2(LOG2E2 * c_own)), 1.0f);         \
    h_own = ov * tc;                                                          \
    H[0] = h_own;                                                             \
    H[1] = updpf<DPP_QP(1,0,3,2)>(H[0], H[0]);                                \
    H[2] = updpf<DPP_QP(2,3,0,1)>(H[0], H[0]);                                \
    H[3] = updpf<DPP_QP(2,3,0,1)>(H[1], H[1]);                                \
    _Pragma("unroll")                                                         \
    for (int rr = 0; rr < 4; ++rr) {                                          \
        float yl = updpf<DPP_SHL(4)>(H[rr], H[rr]);                           \
        float yr = updpf<DPP_SHR(4)>(H[rr], H[rr]);                           \
        H[4 + rr] = m4 ? yr : yl;                                             \
    }                                                                         \
} while (0)

// producer: gather chunk CH's 16 emb rows, MFMA vs Wlds, write G vals to DST.
// A row = lm = timestep-in-chunk; C layout col=lm(+16), row=4q+reg (proven).
#define PRODUCE(DST, CH) do {                                                 \
    int tok_ = sent[((CH) * 16 + lm) * BATCHN + b];                           \
    const float* ar_ = emb + (size_t)tok_ * EMBED;                            \
    float4 ua[16], va[16];                                                    \
    _Pragma("unroll")                                                         \
    for (int kc = 0; kc < 16; ++kc) {                                         \
        ua[kc] = *reinterpret_cast<const float4*>(ar_ + kc * 32 + q * 8);     \
        va[kc] = *reinterpret_cast<const float4*>(ar_ + kc * 32 + q * 8 + 4); \
    }                                                                         \
    f32x4 acc0 = {0.f,0.f,0.f,0.f};                                           \
    f32x4 acc1 = {0.f,0.f,0.f,0.f};                                           \
    _Pragma("unroll")                                                         \
    for (int kc = 0; kc < 16; ++kc) {                                         \
        bf16x8 a_ = cvt8(ua[kc], va[kc]);                                     \
        const int kl_ = kc * 32 + q * 8;                                      \
        bf16x8 b0_ = *reinterpret_cast<const bf16x8*>(&Wlds[lm][kl_]);        \
        bf16x8 b1_ = *reinterpret_cast<const bf16x8*>(&Wlds[16 + lm][kl_]);   \
        acc0 = __builtin_amdgcn_mfma_f32_16x16x32_bf16(a_, b0_, acc0, 0,0,0); \
        acc1 = __builtin_amdgcn_mfma_f32_16x16x32_bf16(a_, b1_, acc1, 0,0,0); \
    }                                                                         \
    _Pragma("unroll")                                                         \
    for (int r_ = 0; r_ < 4; ++r_) {                                          \
        (DST)[(4*q + r_) * GBSTR + lm]      = fmaf(acc0[r_], INV2PI, bc0);    \
        (DST)[(4*q + r_) * GBSTR + 16 + lm] = fmaf(acc1[r_], INV2PI, bc1);    \
    }                                                                         \
} while (0)

// ---------------------------------------------------------------------------
// Wave-specialized fused kernel (r17 structure): 256 blocks x 128 threads.
//   wave 0 (consumer): serial LSTM chain, r17 lane layout l32 = g*8+j.
//   wave 1 (producer): emb gather + MFMA for chunk c+1 while consumer runs c.
//   ONLY change vs r17: consumer reads the chunk's 16 G values into registers
//   up-front (static indexing) instead of per-step LDS reads.
// ---------------------------------------------------------------------------
__global__ __launch_bounds__(128, 1)
void k_fused(const int* __restrict__ sent, const float* __restrict__ emb,
             const float* __restrict__ Wf, const float* __restrict__ Wi,
             const float* __restrict__ Wu, const float* __restrict__ Wo,
             const float* __restrict__ bf, const float* __restrict__ bi,
             const float* __restrict__ bu, const float* __restrict__ bo,
             const float* __restrict__ thf, const float* __restrict__ thi,
             const float* __restrict__ thu, const float* __restrict__ tho,
             float* __restrict__ out)
{
    __shared__ short Wlds[32][WROW];        // 33.5 KB bf16, [c][k 0..511]
    __shared__ float gbuf[2][16 * GBSTR];   // 5.1 KB double-buffered chunk

    const int tid = threadIdx.x;            // 0..127
    const int b   = blockIdx.x;             // batch row
    const bool producer = (tid >= 64);
    const int l32 = tid & 31;               // consumer lane
    const int g   = l32 >> 3;
    const int j   = l32 & 7;
    const int lm  = tid & 15;               // producer A-row / B-col
    const int q   = (tid >> 4) & 3;         // producer k-quarter

    // ---- stage W -> bf16 LDS, 128 threads cooperatively ----
    {
        const int c = tid & 31, seg = tid >> 5;     // seg 0..3 x 128 floats
        const int gg = c >> 3, jj = c & 7;
        const float* W = (gg==0) ? Wf : (gg==1) ? Wi : (gg==2) ? Wu : Wo;
        const float* src = W + (size_t)jj * DIN + seg * 128;
        #pragma unroll
        for (int p = 0; p < 16; ++p) {
            float4 u = *reinterpret_cast<const float4*>(src + p * 8);
            float4 v = *reinterpret_cast<const float4*>(src + p * 8 + 4);
            *reinterpret_cast<bf16x8*>(&Wlds[c][seg * 128 + p * 8]) = cvt8(u, v);
        }
    }

    // ---- role-specific persistent state ----
    float Whp[8], H[8];
    float c_own = 0.f, h_own = 0.f;
    float bc0 = 0.f, bc1 = 0.f;
    bool  m1 = false, m2 = false, m4 = false, jz = false;
    float ek = 0.f, sk = 0.f, ok = 0.f;

    if (producer) {
        const int g0 = lm >> 3, j0 = lm & 7;        // col lm -> gate 0/1
        const float* B0 = (g0==0) ? bf  : bi;
        const float* T0 = (g0==0) ? thf : thi;
        bc0 = (B0[j0] + T0[j0]) * INV2PI;
        const float* B1 = (g0==0) ? bu  : bo;       // col 16+lm -> gate 2/3
        const float* T1 = (g0==0) ? thu : tho;
        bc1 = (B1[j0] + T1[j0]) * INV2PI;
    } else {
        const float* Wsel = (g==0) ? Wf : (g==1) ? Wi : (g==2) ? Wu : Wo;
        #pragma unroll
        for (int rr = 0; rr < 8; ++rr) {
            Whp[rr] = Wsel[j * DIN + EMBED + (j ^ rr)] * INV2PI;
            H[rr]   = 0.f;
        }
        m1 = (j >= 1); m2 = (j >= 2); m4 = (j >= 4); jz = (j == 0);
        const bool isU = (g == 2);
        ek = isU ? LOG2E2 : -LOG2E;
        sk = isU ? -2.0f  : 1.0f;
        ok = isU ? 1.0f   : 0.0f;
    }
    __syncthreads();                         // Wlds ready

    if (producer) PRODUCE(&gbuf[0][0], 0);   // prologue: chunk 0
    __syncthreads();                         // gbuf[0] ready

    #pragma unroll 1
    for (int c = 0; c < 8; ++c) {
        if (producer) {
            if (c < 7) PRODUCE(&gbuf[(c + 1) & 1][0], c + 1);
        } else {
            const float* gc = &gbuf[c & 1][l32];
            float gvv[16];
            #pragma unroll
            for (int s = 0; s < 16; ++s) gvv[s] = gc[s * GBSTR];
            #pragma unroll
            for (int s = 0; s < 16; ++s) QSTEP(gvv[s]);
        }
        __syncthreads();
    }

    if (tid < 8) out[b * NQ + tid] = h_own;  // consumer lanes 0-7: g=0, j=tid
}

// ---------------------------------------------------------------------------
extern "C" void kernel_launch(void* const* d_in, const int* in_sizes, int n_in,
                              void* d_out, int out_size, void* d_ws, size_t ws_size,
                              hipStream_t stream)
{
    const int*   sent = (const int*)  d_in[0];
    // d_in[1] = features : unused by the reference
    const float* emb  = (const float*)d_in[2];
    const float* Wf   = (const float*)d_in[3];
    const float* bf   = (const float*)d_in[4];
    const float* Wi   = (const float*)d_in[5];
    const float* bi   = (const float*)d_in[6];
    const float* Wu   = (const float*)d_in[7];
    const float* bu   = (const float*)d_in[8];
    const float* Wo   = (const float*)d_in[9];
    const float* bo   = (const float*)d_in[10];
    const float* thf  = (const float*)d_in[11];
    const float* thi  = (const float*)d_in[12];
    const float* thu  = (const float*)d_in[13];
    const float* tho  = (const float*)d_in[14];
    float* out = (float*)d_out;

    k_fused<<<BATCHN, 128, 0, stream>>>(sent, emb, Wf, Wi, Wu, Wo,
                                        bf, bi, bu, bo,
                                        thf, thi, thu, tho, out);
}